// Round 5
// baseline (404.263 us; speedup 1.0000x reference)
//
#include <hip/hip_runtime.h>
#include <math.h>

// VectorQuantizer — bit-exact emulation of the numpy fp32 reference (proven R2-R4):
//   d[n,k] = fl32( fl32(x2[n]+c2[k]) - fl32(2 * fl32(exact_dot)) ), idx = first argmin
// R4's k-split (4 waves/SIMD) was right but spilled x[]/sq[] to scratch under the
// 128-VGPR cap (VGPR=64, 77MB scratch writes): np_pairwise_sum64(float*) forced
// materialization of sq[64] alongside x[64]. R5: rolling 8-accumulator x2 (numpy
// order, no sq array), reference-passed register arrays, transposed LDS candidate
// buffers ([CAP][256] -> conflict-free).

#define N_CODES   512
#define CODE_DIM  64
#define CH_STRIDE 4096                      // floats between channels
#define B_STRIDE  (CODE_DIM * CH_STRIDE)    // floats between batches
#define N_GW      1024                      // (b,h) row-groups
#define KCHUNK    128                       // codes per wave (4 waves/block)
#define CAP       8                         // candidate buffer per lane

// numpy pairwise_sum for n=64 (loops.c.src) — setup kernel only (not perf-critical).
__device__ __forceinline__ float np_pairwise_sum64(const float* a) {
    float r[8];
#pragma unroll
    for (int j = 0; j < 8; ++j) r[j] = a[j];
#pragma unroll
    for (int i = 8; i < 64; i += 8) {
#pragma unroll
        for (int j = 0; j < 8; ++j) r[j] = __fadd_rn(r[j], a[i + j]);
    }
    return __fadd_rn(__fadd_rn(__fadd_rn(r[0], r[1]), __fadd_rn(r[2], r[3])),
                     __fadd_rn(__fadd_rn(r[4], r[5]), __fadd_rn(r[6], r[7])));
}

__global__ void vq_setup_kernel(const float* __restrict__ cb, float* __restrict__ c2) {
    const int k = blockIdx.x * blockDim.x + threadIdx.x;
    if (k < N_CODES) {
        const float* row = cb + k * CODE_DIM;
        float sq[CODE_DIM];
#pragma unroll
        for (int j = 0; j < CODE_DIM; ++j) sq[j] = __fmul_rn(row[j], row[j]);
        c2[k] = np_pairwise_sum64(sq);
    }
}

// Exact dk — identical arithmetic to the R2 kernel that passed. x by reference,
// constant indices only (SROA keeps it in VGPRs).
__device__ __forceinline__ float exact_dk(const float* __restrict__ cb,
                                          const float* __restrict__ c2,
                                          const float (&x)[CODE_DIM], float x2, int k) {
    const float* crow = cb + (size_t)k * CODE_DIM;
    double a0 = 0.0, a1 = 0.0, a2 = 0.0, a3 = 0.0;
#pragma unroll
    for (int j = 0; j < CODE_DIM; j += 4) {
        a0 = fma((double)crow[j + 0], (double)x[j + 0], a0);
        a1 = fma((double)crow[j + 1], (double)x[j + 1], a1);
        a2 = fma((double)crow[j + 2], (double)x[j + 2], a2);
        a3 = fma((double)crow[j + 3], (double)x[j + 3], a3);
    }
    const double dot = (a0 + a1) + (a2 + a3);
    const float  ein = (float)dot;
    const float  tmp = __fadd_rn(x2, c2[k]);
    return __fsub_rn(tmp, __fmul_rn(2.0f, ein));
}

// One block per (b,h). lane = w (coalesced 256B channel loads). Wave wid scans
// codes [wid*128, wid*128+128). Codebook reads are wave-uniform -> scalar loads.
__global__ __launch_bounds__(256, 4)
void vq_main_kernel(const float* __restrict__ in,
                    const float* __restrict__ cb,
                    const float* __restrict__ c2,
                    float* __restrict__ out) {
    __shared__ float s_cdk[CAP][256];   // [entry][thread]: conflict-free
    __shared__ int   s_cki[CAP][256];
    __shared__ float s_rb[4][64];       // per-wave chunk winner dk
    __shared__ int   s_ri[4][64];       // per-wave chunk winner k

    const int tid  = threadIdx.x;
    const int lane = tid & 63;
    const int wid  = tid >> 6;          // 0..3 -> k-chunk
    const int gw   = blockIdx.x;        // 0..1023
    const int b    = gw >> 6;
    const int h    = gw & 63;

    // x[0..63] in VGPRs (stride-4096 loads, coalesced across lanes; 4 waves read
    // the same lines -> L1 hits).
    const float* xin = in + (size_t)b * B_STRIDE + (size_t)h * 64 + lane;
    float x[CODE_DIM];
#pragma unroll
    for (int c = 0; c < CODE_DIM; ++c) x[c] = xin[(size_t)c * CH_STRIDE];

    // x2 = np.sum(x*x) in numpy pairwise order, rolling 8 accumulators:
    //   r[j] = fl(x[j]^2); r[j] = fl(r[j] + fl(x[i+j]^2));  (no sq[64] array)
    float r[8];
#pragma unroll
    for (int j = 0; j < 8; ++j) r[j] = __fmul_rn(x[j], x[j]);
#pragma unroll
    for (int i = 8; i < 64; i += 8) {
#pragma unroll
        for (int j = 0; j < 8; ++j)
            r[j] = __fadd_rn(r[j], __fmul_rn(x[i + j], x[i + j]));
    }
    const float x2 = __fadd_rn(
        __fadd_rn(__fadd_rn(r[0], r[1]), __fadd_rn(r[2], r[3])),
        __fadd_rn(__fadd_rn(r[4], r[5]), __fadd_rn(r[6], r[7])));

    // --- Pass 1: fp32 fast scan of this wave's 128-code chunk ----------------
    // Capture any k with dk_fast <= chunk_best + thr, thr = 4.5*ulp(best)+8e-6
    // (>= 2*(fast-scan error) incl. binade edge) => exact chunk argmin captured.
    const int k0 = wid * KCHUNK;
    float best = INFINITY, cut = INFINITY;
    int   count = 0, overflow = 0;

#pragma unroll 2
    for (int kk = 0; kk < KCHUNK; ++kk) {
        const int k = k0 + kk;
        const float* crow = cb + (size_t)k * CODE_DIM;
        float a0 = 0.f, a1 = 0.f, a2 = 0.f, a3 = 0.f;
#pragma unroll
        for (int j = 0; j < CODE_DIM; j += 4) {
            a0 = fmaf(x[j + 0], crow[j + 0], a0);
            a1 = fmaf(x[j + 1], crow[j + 1], a1);
            a2 = fmaf(x[j + 2], crow[j + 2], a2);
            a3 = fmaf(x[j + 3], crow[j + 3], a3);
        }
        const float dot = __fadd_rn(__fadd_rn(a0, a1), __fadd_rn(a2, a3));
        const float dk  = __fsub_rn(__fadd_rn(x2, c2[k]), __fmul_rn(2.0f, dot));

        const bool ins = (dk <= cut);   // old cut: conservative superset
        if (dk < best) {
            best = dk;
            const float g = __uint_as_float(__float_as_uint(best) & 0xFF800000u)
                            * 1.1920929e-7f;          // ulp(best)
            cut = __fadd_rn(best, __fmaf_rn(4.5f, g, 8e-6f));
        }
        if (ins) {
            if (count == CAP) {         // compact: drop entries above current cut
                int nc = 0;
#pragma unroll 1
                for (int i = 0; i < CAP; ++i) {
                    const float d  = s_cdk[i][tid];
                    const int   ki = s_cki[i][tid];
                    if (d <= cut) { s_cdk[nc][tid] = d; s_cki[nc][tid] = ki; ++nc; }
                }
                count = nc;
            }
            if (count < CAP) {
                s_cdk[count][tid] = dk;
                s_cki[count][tid] = k;
                ++count;
            } else {
                overflow = 1;
            }
        }
    }

    // --- Pass 2: exact re-resolution of this chunk's candidates --------------
    float ex_best = INFINITY;
    int   bi = k0;
#pragma unroll 1
    for (int i = 0; i < count; ++i) {
        const int   k  = s_cki[i][tid];
        const float dk = exact_dk(cb, c2, x, x2, k);
        if (dk < ex_best) { ex_best = dk; bi = k; }   // ascending k => first-min
    }
    if (__builtin_amdgcn_ballot_w64(overflow != 0)) { // ~never: exact rescan of chunk
        if (overflow) {
            ex_best = INFINITY; bi = k0;
#pragma unroll 1
            for (int kk = 0; kk < KCHUNK; ++kk) {
                const float dk = exact_dk(cb, c2, x, x2, k0 + kk);
                if (dk < ex_best) { ex_best = dk; bi = k0 + kk; }
            }
        }
    }

    // --- Combine the 4 chunk winners (min dk; ties -> lower chunk => lower k) -
    s_rb[wid][lane] = ex_best;
    s_ri[wid][lane] = bi;
    __syncthreads();
    float fb = s_rb[0][lane];
    int   fi = s_ri[0][lane];
#pragma unroll
    for (int w = 1; w < 4; ++w) {
        const float d  = s_rb[w][lane];
        const int   i2 = s_ri[w][lane];
        if (d < fb) { fb = d; fi = i2; }   // strict < keeps earliest chunk on ties
    }

    // --- Output: each wave writes 16 of the 64 rows (coalesced 256B each) ----
    const size_t n0 = (size_t)gw * 64;
#pragma unroll 1
    for (int rr = 0; rr < 16; ++rr) {
        const int row  = wid * 16 + rr;
        const int idxr = __shfl(fi, row, 64);
        out[(n0 + row) * CODE_DIM + lane] = cb[(size_t)idxr * CODE_DIM + lane];
    }
}

extern "C" void kernel_launch(void* const* d_in, const int* in_sizes, int n_in,
                              void* d_out, int out_size, void* d_ws, size_t ws_size,
                              hipStream_t stream) {
    const float* in  = (const float*)d_in[0];   // (16,64,64,64) fp32
    const float* cb  = (const float*)d_in[1];   // (512,64) fp32
    float*       out = (float*)d_out;           // (16,64,64,64) fp32
    float*       c2  = (float*)d_ws;            // 512 floats scratch

    vq_setup_kernel<<<dim3(2), dim3(256), 0, stream>>>(cb, c2);
    vq_main_kernel<<<dim3(N_GW), dim3(256), 0, stream>>>(in, cb, c2, out);
}

// Round 6
// 236.920 us; speedup vs baseline: 1.7063x; 1.7063x over previous
//
#include <hip/hip_runtime.h>
#include <math.h>

// VectorQuantizer — bit-exact emulation of the numpy fp32 reference (proven R2-R5):
//   d[n,k] = fl32( fl32(x2[n]+c2[k]) - fl32(2 * fl32(exact_dot)) ), idx = first argmin
// R4/R5 regression diagnosed: k0 = (tid>>6)*128 is wave-uniform in fact but
// divergent to the compiler -> codebook rows fetched with per-lane vector loads
// -> +64 VGPRs of prefetch -> x[64] demoted to scratch (VGPR=64, 61MB scratch).
// R6: readfirstlane(k0) restores the provably-uniform s_load path (codebook row
// in SGPRs, as in R3 where SGPR=112/VGPR=84), launch_bounds (256,2) gives the
// allocator headroom. k-split over 4 waves kept for occupancy (R4's valid idea).

#define N_CODES   512
#define CODE_DIM  64
#define CH_STRIDE 4096                      // floats between channels
#define B_STRIDE  (CODE_DIM * CH_STRIDE)    // floats between batches
#define N_GW      1024                      // (b,h) row-groups
#define KCHUNK    128                       // codes per wave (4 waves/block)
#define CAP       8                         // candidate buffer per lane

// numpy pairwise_sum for n=64 (loops.c.src) — setup kernel only.
__device__ __forceinline__ float np_pairwise_sum64(const float* a) {
    float r[8];
#pragma unroll
    for (int j = 0; j < 8; ++j) r[j] = a[j];
#pragma unroll
    for (int i = 8; i < 64; i += 8) {
#pragma unroll
        for (int j = 0; j < 8; ++j) r[j] = __fadd_rn(r[j], a[i + j]);
    }
    return __fadd_rn(__fadd_rn(__fadd_rn(r[0], r[1]), __fadd_rn(r[2], r[3])),
                     __fadd_rn(__fadd_rn(r[4], r[5]), __fadd_rn(r[6], r[7])));
}

__global__ void vq_setup_kernel(const float* __restrict__ cb, float* __restrict__ c2) {
    const int k = blockIdx.x * blockDim.x + threadIdx.x;
    if (k < N_CODES) {
        const float* row = cb + k * CODE_DIM;
        float sq[CODE_DIM];
#pragma unroll
        for (int j = 0; j < CODE_DIM; ++j) sq[j] = __fmul_rn(row[j], row[j]);
        c2[k] = np_pairwise_sum64(sq);
    }
}

// Exact dk — identical arithmetic to the R2 kernel that passed.
__device__ __forceinline__ float exact_dk(const float* __restrict__ cb,
                                          const float* __restrict__ c2,
                                          const float (&x)[CODE_DIM], float x2, int k) {
    const float* crow = cb + (size_t)k * CODE_DIM;
    double a0 = 0.0, a1 = 0.0, a2 = 0.0, a3 = 0.0;
#pragma unroll
    for (int j = 0; j < CODE_DIM; j += 4) {
        a0 = fma((double)crow[j + 0], (double)x[j + 0], a0);
        a1 = fma((double)crow[j + 1], (double)x[j + 1], a1);
        a2 = fma((double)crow[j + 2], (double)x[j + 2], a2);
        a3 = fma((double)crow[j + 3], (double)x[j + 3], a3);
    }
    const double dot = (a0 + a1) + (a2 + a3);
    const float  ein = (float)dot;
    const float  tmp = __fadd_rn(x2, c2[k]);
    return __fsub_rn(tmp, __fmul_rn(2.0f, ein));
}

// One block per (b,h). lane = w (coalesced 256B channel loads). Wave wid scans
// codes [k0, k0+128) with k0 forced into an SGPR -> codebook rows via s_load.
__global__ __launch_bounds__(256, 2)
void vq_main_kernel(const float* __restrict__ in,
                    const float* __restrict__ cb,
                    const float* __restrict__ c2,
                    float* __restrict__ out) {
    __shared__ float s_cdk[CAP][256];   // [entry][thread]: conflict-free
    __shared__ int   s_cki[CAP][256];
    __shared__ float s_rb[4][64];       // per-wave chunk winner dk
    __shared__ int   s_ri[4][64];       // per-wave chunk winner k

    const int tid  = threadIdx.x;
    const int lane = tid & 63;
    const int wid  = tid >> 6;          // 0..3 -> k-chunk (wave-uniform in fact)
    const int gw   = blockIdx.x;        // 0..1023
    const int b    = gw >> 6;
    const int h    = gw & 63;

    // x[0..63] in VGPRs (stride-4096 loads, coalesced across lanes).
    const float* xin = in + (size_t)b * B_STRIDE + (size_t)h * 64 + lane;
    float x[CODE_DIM];
#pragma unroll
    for (int c = 0; c < CODE_DIM; ++c) x[c] = xin[(size_t)c * CH_STRIDE];

    // x2 = np.sum(x*x) in numpy pairwise order, rolling 8 accumulators.
    float r[8];
#pragma unroll
    for (int j = 0; j < 8; ++j) r[j] = __fmul_rn(x[j], x[j]);
#pragma unroll
    for (int i = 8; i < 64; i += 8) {
#pragma unroll
        for (int j = 0; j < 8; ++j)
            r[j] = __fadd_rn(r[j], __fmul_rn(x[i + j], x[i + j]));
    }
    const float x2 = __fadd_rn(
        __fadd_rn(__fadd_rn(r[0], r[1]), __fadd_rn(r[2], r[3])),
        __fadd_rn(__fadd_rn(r[4], r[5]), __fadd_rn(r[6], r[7])));

    // k0 in an SGPR: wid is wave-uniform, so readfirstlane is an identity.
    // This makes crow provably uniform -> s_load path (codebook row in SGPRs),
    // keeping VGPR pressure low enough that x[] stays in registers.
    const int k0 = __builtin_amdgcn_readfirstlane(wid) * KCHUNK;

    // --- Pass 1: fp32 fast scan of this wave's 128-code chunk ----------------
    // Capture any k with dk_fast <= chunk_best + thr, thr = 4.5*ulp(best)+8e-6
    // (>= 2*(fast-scan error) incl. binade edge) => exact chunk argmin captured.
    float best = INFINITY, cut = INFINITY;
    int   count = 0, overflow = 0;

#pragma unroll 2
    for (int kk = 0; kk < KCHUNK; ++kk) {
        const int k = k0 + kk;
        const float* crow = cb + (size_t)k * CODE_DIM;
        float a0 = 0.f, a1 = 0.f, a2 = 0.f, a3 = 0.f;
#pragma unroll
        for (int j = 0; j < CODE_DIM; j += 4) {
            a0 = fmaf(x[j + 0], crow[j + 0], a0);
            a1 = fmaf(x[j + 1], crow[j + 1], a1);
            a2 = fmaf(x[j + 2], crow[j + 2], a2);
            a3 = fmaf(x[j + 3], crow[j + 3], a3);
        }
        const float dot = __fadd_rn(__fadd_rn(a0, a1), __fadd_rn(a2, a3));
        const float dk  = __fsub_rn(__fadd_rn(x2, c2[k]), __fmul_rn(2.0f, dot));

        const bool ins = (dk <= cut);   // old cut: conservative superset
        if (dk < best) {
            best = dk;
            const float g = __uint_as_float(__float_as_uint(best) & 0xFF800000u)
                            * 1.1920929e-7f;          // ulp(best)
            cut = __fadd_rn(best, __fmaf_rn(4.5f, g, 8e-6f));
        }
        if (ins) {
            if (count == CAP) {         // compact: drop entries above current cut
                int nc = 0;
#pragma unroll 1
                for (int i = 0; i < CAP; ++i) {
                    const float d  = s_cdk[i][tid];
                    const int   ki = s_cki[i][tid];
                    if (d <= cut) { s_cdk[nc][tid] = d; s_cki[nc][tid] = ki; ++nc; }
                }
                count = nc;
            }
            if (count < CAP) {
                s_cdk[count][tid] = dk;
                s_cki[count][tid] = k;
                ++count;
            } else {
                overflow = 1;
            }
        }
    }

    // --- Pass 2: exact re-resolution of this chunk's candidates --------------
    float ex_best = INFINITY;
    int   bi = k0;
#pragma unroll 1
    for (int i = 0; i < count; ++i) {
        const int   k  = s_cki[i][tid];
        const float dk = exact_dk(cb, c2, x, x2, k);
        if (dk < ex_best) { ex_best = dk; bi = k; }   // ascending k => first-min
    }
    if (__builtin_amdgcn_ballot_w64(overflow != 0)) { // ~never: exact rescan of chunk
        if (overflow) {
            ex_best = INFINITY; bi = k0;
#pragma unroll 1
            for (int kk = 0; kk < KCHUNK; ++kk) {
                const float dk = exact_dk(cb, c2, x, x2, k0 + kk);
                if (dk < ex_best) { ex_best = dk; bi = k0 + kk; }
            }
        }
    }

    // --- Combine the 4 chunk winners (min dk; ties -> lower chunk => lower k) -
    s_rb[wid][lane] = ex_best;
    s_ri[wid][lane] = bi;
    __syncthreads();
    float fb = s_rb[0][lane];
    int   fi = s_ri[0][lane];
#pragma unroll
    for (int w = 1; w < 4; ++w) {
        const float d  = s_rb[w][lane];
        const int   i2 = s_ri[w][lane];
        if (d < fb) { fb = d; fi = i2; }   // strict < keeps earliest chunk on ties
    }

    // --- Output: each wave writes 16 of the 64 rows (coalesced 256B each) ----
    const size_t n0 = (size_t)gw * 64;
#pragma unroll 1
    for (int rr = 0; rr < 16; ++rr) {
        const int row  = wid * 16 + rr;
        const int idxr = __shfl(fi, row, 64);
        out[(n0 + row) * CODE_DIM + lane] = cb[(size_t)idxr * CODE_DIM + lane];
    }
}

extern "C" void kernel_launch(void* const* d_in, const int* in_sizes, int n_in,
                              void* d_out, int out_size, void* d_ws, size_t ws_size,
                              hipStream_t stream) {
    const float* in  = (const float*)d_in[0];   // (16,64,64,64) fp32
    const float* cb  = (const float*)d_in[1];   // (512,64) fp32
    float*       out = (float*)d_out;           // (16,64,64,64) fp32
    float*       c2  = (float*)d_ws;            // 512 floats scratch

    vq_setup_kernel<<<dim3(2), dim3(256), 0, stream>>>(cb, c2);
    vq_main_kernel<<<dim3(N_GW), dim3(256), 0, stream>>>(in, cb, c2, out);
}